// Round 6
// baseline (411.595 us; speedup 1.0000x reference)
//
#include <hip/hip_runtime.h>
#include <math.h>

// ============================================================================
// ChannelAttention — Gram restructure, bf16 MFMA big GEMMs.
// R6: conflict-free k_conv (u32 token-pair packed transpose), symmetric
//     k_gram (6 lower-triangle tiles + mirrored stores, -33% MFMA).
// ============================================================================

#define B_    4
#define NTOK  16384
#define C_    384
#define NH    4
#define DH    96

typedef __attribute__((ext_vector_type(8))) short short8;
typedef __attribute__((ext_vector_type(4))) float f32x4;
typedef __attribute__((ext_vector_type(4))) unsigned short ushort4v;
typedef __attribute__((ext_vector_type(8))) unsigned short ushort8v;
typedef __attribute__((ext_vector_type(4))) unsigned int uint4v;

// ---- ws byte offsets (ws = 384 MiB confirmed round 3) ----
#define XH_B   0ull
#define XHT_B  50331648ull            // + B*N*C*2
#define GP_B   100663296ull           // 16 grp partials (chunk x batch), fp32
#define G_B    138412032ull
#define P_B    140771328ull
#define SSQ_B  145489920ull
#define ATT_B  145502208ull           // S, then attn in-place (16*96*96 f32)
#define T_B    146092032ull           // T (4*384*384 f32)
#define MPH_B  150810624ull

__device__ inline unsigned short f2bf(float f) {
    unsigned u = __float_as_uint(f);
    u += 0x7FFFu + ((u >> 16) & 1u);          // RNE
    return (unsigned short)(u >> 16);
}

__device__ inline void load16(const void* g, void* l) {
    __builtin_amdgcn_global_load_lds(
        (const __attribute__((address_space(1))) unsigned int*)g,
        (__attribute__((address_space(3))) unsigned int*)l, 16, 0, 0);
}

// ---------------------------------------------------------------------------
// X fp32 -> Xh (natural) + XhT (transposed) bf16.  64x64 tiles.
// Token-pairs packed as u32 in LDS [64 ch][33 dw] => all LDS ops <=2-way.
// grid (256, 6, 4), 256 threads.
// ---------------------------------------------------------------------------
__global__ __launch_bounds__(256) void k_conv(const float* __restrict__ X,
                                              unsigned short* __restrict__ Xh,
                                              unsigned short* __restrict__ XhT) {
    __shared__ __align__(16) unsigned int Tp[64 * 33];
    const int tid = threadIdx.x;
    const int t0 = blockIdx.x * 64, c0 = blockIdx.y * 64, b = blockIdx.z;
    const int tp = tid >> 4, cg = tid & 15;
#pragma unroll
    for (int i = 0; i < 2; ++i) {
        const int tpair = tp + 16 * i;
        const int t = t0 + tpair * 2;
        const float4 v0 = *(const float4*)(X + ((size_t)(b * NTOK + t))     * C_ + c0 + cg * 4);
        const float4 v1 = *(const float4*)(X + ((size_t)(b * NTOK + t + 1)) * C_ + c0 + cg * 4);
        const unsigned short h00 = f2bf(v0.x), h01 = f2bf(v0.y), h02 = f2bf(v0.z), h03 = f2bf(v0.w);
        const unsigned short h10 = f2bf(v1.x), h11 = f2bf(v1.y), h12 = f2bf(v1.z), h13 = f2bf(v1.w);
        ushort4v a; a.x = h00; a.y = h01; a.z = h02; a.w = h03;
        ushort4v c; c.x = h10; c.y = h11; c.z = h12; c.w = h13;
        *(ushort4v*)(Xh + ((size_t)(b * NTOK + t))     * C_ + c0 + cg * 4) = a;
        *(ushort4v*)(Xh + ((size_t)(b * NTOK + t + 1)) * C_ + c0 + cg * 4) = c;
        Tp[(cg * 4 + 0) * 33 + tpair] = (unsigned)h00 | ((unsigned)h10 << 16);
        Tp[(cg * 4 + 1) * 33 + tpair] = (unsigned)h01 | ((unsigned)h11 << 16);
        Tp[(cg * 4 + 2) * 33 + tpair] = (unsigned)h02 | ((unsigned)h12 << 16);
        Tp[(cg * 4 + 3) * 33 + tpair] = (unsigned)h03 | ((unsigned)h13 << 16);
    }
    __syncthreads();
    const int c = tid >> 2, seg = tid & 3;
    unsigned int w[8];
#pragma unroll
    for (int k = 0; k < 8; ++k) w[k] = Tp[c * 33 + seg * 8 + k];
    unsigned int* dst = (unsigned int*)(XhT + ((size_t)(b * C_ + c0 + c)) * NTOK + t0 + seg * 16);
    uint4v s0; s0.x = w[0]; s0.y = w[1]; s0.z = w[2]; s0.w = w[3];
    uint4v s1; s1.x = w[4]; s1.y = w[5]; s1.z = w[6]; s1.w = w[7];
    *(uint4v*)dst       = s0;
    *((uint4v*)dst + 1) = s1;
}

// ---------------------------------------------------------------------------
// Gpart[grp]: 6 lower-triangle 128x128 tiles of XhT-stripe @ XhT-stripe^T
// over a 1024-token chunk (MFMA 16x16x32).  Off-diag tiles mirror-stored
// (G exactly symmetric).  384 blocks (8 grps x 6 tiles per XCD), 4 waves.
// ---------------------------------------------------------------------------
__global__ __launch_bounds__(256, 2) void k_gram_mfma(const unsigned short* __restrict__ XhT,
                                                      float* __restrict__ Gpart) {
    __shared__ __align__(16) unsigned char sm[32768];   // A rows [0,16K), B rows [16K,32K)
    const int l = blockIdx.x;
    const int xcd = l & 7, slot = l >> 3;               // 48 slots per XCD
    const int grp = xcd * 8 + slot / 6, tile = slot % 6;
    const int chunk = grp >> 2, b = grp & 3;
    const int ti = (tile == 0) ? 0 : (tile < 3 ? 1 : 2);
    const int tj = tile - (ti * (ti + 1)) / 2;
    const int tid = threadIdx.x;
    const int lane = tid & 63, wid = tid >> 6;
    const int wr = wid >> 1, wc = wid & 1;

    const int e = (lane & 7) ^ (lane >> 3);   // inverse-swizzled source slot
    const int rsub = lane >> 3;

    const size_t rowb = (size_t)NTOK * 2;
    const unsigned char* Abase = (const unsigned char*)XhT + (size_t)(b * C_ + ti * 128) * rowb;
    const unsigned char* Bbase = (const unsigned char*)XhT + (size_t)(b * C_ + tj * 128) * rowb;

    f32x4 acc[4][4];
#pragma unroll
    for (int i = 0; i < 4; i++)
#pragma unroll
        for (int j = 0; j < 4; j++) acc[i][j] = (f32x4)(0.f);

    for (int ks = 0; ks < 16; ++ks) {
        const size_t colb = (size_t)(chunk * 1024 + ks * 64) * 2 + (size_t)e * 16;
        __syncthreads();
#pragma unroll
        for (int call = 0; call < 4; ++call) {
            const int row = wid * 32 + call * 8 + rsub;
            load16(Abase + (size_t)row * rowb + colb, sm + (wid * 32 + call * 8) * 128);
            load16(Bbase + (size_t)row * rowb + colb, sm + 16384 + (wid * 32 + call * 8) * 128);
        }
        __syncthreads();
#pragma unroll
        for (int p = 0; p < 2; ++p) {
            const int s = p * 4 + (lane >> 4);
            short8 av[4], bv[4];
#pragma unroll
            for (int fi = 0; fi < 4; ++fi) {
                const int c = wr * 64 + fi * 16 + (lane & 15);
                av[fi] = *(const short8*)(sm + c * 128 + ((s ^ (c & 7)) << 4));
            }
#pragma unroll
            for (int fj = 0; fj < 4; ++fj) {
                const int c = wc * 64 + fj * 16 + (lane & 15);
                bv[fj] = *(const short8*)(sm + 16384 + c * 128 + ((s ^ (c & 7)) << 4));
            }
#pragma unroll
            for (int fi = 0; fi < 4; ++fi)
#pragma unroll
                for (int fj = 0; fj < 4; ++fj)
                    acc[fi][fj] = __builtin_amdgcn_mfma_f32_16x16x32_bf16(av[fi], bv[fj], acc[fi][fj], 0, 0, 0);
        }
    }
    // D layout (m89): col = lane&15, row = (lane>>4)*4 + reg
    float* gp = Gpart + (size_t)grp * (C_ * C_);
    const int r0 = (lane >> 4) * 4, cc = lane & 15;
#pragma unroll
    for (int fi = 0; fi < 4; ++fi) {
        const int ci = ti * 128 + wr * 64 + fi * 16 + r0;
#pragma unroll
        for (int fj = 0; fj < 4; ++fj) {
            const int cj = tj * 128 + wc * 64 + fj * 16 + cc;
#pragma unroll
            for (int r = 0; r < 4; ++r)
                gp[(size_t)(ci + r) * C_ + cj] = acc[fi][fj][r];
        }
    }
    if (ti != tj) {   // mirror (exact copy: G symmetric)
#pragma unroll
        for (int fi = 0; fi < 4; ++fi) {
            const int cib = ti * 128 + wr * 64 + fi * 16 + r0;
#pragma unroll
            for (int fj = 0; fj < 4; ++fj) {
                const int cjb = tj * 128 + wc * 64 + fj * 16 + cc;
                *(f32x4*)(gp + (size_t)cjb * C_ + cib) = acc[fi][fj];
            }
        }
    }
}

__global__ __launch_bounds__(256) void k_reduceG(const float* __restrict__ Gpart,
                                                 float* __restrict__ G) {
    const size_t eo = ((size_t)blockIdx.x * 256 + threadIdx.x) * 4;
    float4 s = *(const float4*)(Gpart + eo);
#pragma unroll
    for (int c = 1; c < 16; ++c) {
        const float4 v = *(const float4*)(Gpart + (size_t)c * (B_ * C_ * C_) + eo);
        s.x += v.x; s.y += v.y; s.z += v.z; s.w += v.w;
    }
    *(float4*)(G + eo) = s;
}

// ---------------------------------------------------------------------------
// P[sel][b][m][n] = sum_k W_sel[m][k] * G_b[n][k]   (G symmetric)
// 64x64 tiles, 4x4 microtile.  grid (6,6,8), 256 threads.
// ---------------------------------------------------------------------------
__global__ __launch_bounds__(256) void k_P64(const float* __restrict__ Wqkv,
                                             const float* __restrict__ G,
                                             float* __restrict__ P) {
    __shared__ float As[32][65];
    __shared__ float Bs[32][65];
    const int tid = threadIdx.x;
    const int sel = blockIdx.z & 1, b = blockIdx.z >> 1;
    const int m0 = blockIdx.x * 64, n0 = blockIdx.y * 64;
    const float* A  = Wqkv + (size_t)sel * C_ * C_;
    const float* Bm = G + (size_t)b * C_ * C_;
    const int lr = tid >> 2, lk = (tid & 3) * 8;
    const int tm = (tid & 15) * 4, tn = (tid >> 4) * 4;
    float acc[4][4];
#pragma unroll
    for (int i = 0; i < 4; i++)
#pragma unroll
        for (int j = 0; j < 4; j++) acc[i][j] = 0.f;

    for (int k0 = 0; k0 < C_; k0 += 32) {
        float4 a0 = *(const float4*)(A  + (size_t)(m0 + lr) * C_ + k0 + lk);
        float4 a1 = *(const float4*)(A  + (size_t)(m0 + lr) * C_ + k0 + lk + 4);
        float4 b0 = *(const float4*)(Bm + (size_t)(n0 + lr) * C_ + k0 + lk);
        float4 b1 = *(const float4*)(Bm + (size_t)(n0 + lr) * C_ + k0 + lk + 4);
        __syncthreads();
        As[lk + 0][lr] = a0.x; As[lk + 1][lr] = a0.y; As[lk + 2][lr] = a0.z; As[lk + 3][lr] = a0.w;
        As[lk + 4][lr] = a1.x; As[lk + 5][lr] = a1.y; As[lk + 6][lr] = a1.z; As[lk + 7][lr] = a1.w;
        Bs[lk + 0][lr] = b0.x; Bs[lk + 1][lr] = b0.y; Bs[lk + 2][lr] = b0.z; Bs[lk + 3][lr] = b0.w;
        Bs[lk + 4][lr] = b1.x; Bs[lk + 5][lr] = b1.y; Bs[lk + 6][lr] = b1.z; Bs[lk + 7][lr] = b1.w;
        __syncthreads();
#pragma unroll
        for (int k = 0; k < 32; k++) {
            float a[4], bb[4];
            *(float4*)&a[0]  = *(const float4*)&As[k][tm];
            *(float4*)&bb[0] = *(const float4*)&Bs[k][tn];
#pragma unroll
            for (int i = 0; i < 4; i++)
#pragma unroll
                for (int j = 0; j < 4; j++)
                    acc[i][j] = fmaf(a[i], bb[j], acc[i][j]);
        }
    }
    float* outp = P + ((size_t)(sel * B_ + b) * C_ + m0 + tm) * C_ + n0 + tn;
#pragma unroll
    for (int i = 0; i < 4; i++) {
        float4 c0 = make_float4(acc[i][0], acc[i][1], acc[i][2], acc[i][3]);
        *(float4*)(outp + (size_t)i * C_) = c0;
    }
}

// ---------------------------------------------------------------------------
// ssq[sel][b][c] = <P[sel][b][c][:], W_{sel}[c][:]>
// ---------------------------------------------------------------------------
__global__ __launch_bounds__(256) void k_diag(const float* __restrict__ P,
                                              const float* __restrict__ Wqkv,
                                              float* __restrict__ ssq) {
    int g = blockIdx.x * 256 + threadIdx.x;
    int sel = g / (B_ * C_), rem = g % (B_ * C_), b = rem / C_, c = rem % C_;
    const float* pr = P + ((size_t)(sel * B_ + b) * C_ + c) * C_;
    const float* wr = Wqkv + ((size_t)sel * C_ + c) * C_;
    float s = 0.f;
#pragma unroll 4
    for (int k = 0; k < C_; k += 4) {
        float4 pv = *(const float4*)(pr + k);
        float4 wv = *(const float4*)(wr + k);
        s += pv.x * wv.x + pv.y * wv.y + pv.z * wv.z + pv.w * wv.w;
    }
    ssq[g] = s;
}

// ---------------------------------------------------------------------------
// S[bh][r][c] = sum_k P1[b][h*96+r][k] * Wk[h*96+c][k]
// grid (6 col-strips of 16, 16 bh), 256 threads; 6 rows x 1 col per thread.
// ---------------------------------------------------------------------------
__global__ __launch_bounds__(256) void k_S(const float* __restrict__ P,
                                           const float* __restrict__ Wqkv,
                                           float* __restrict__ S) {
    __shared__ float Ps[32 * 97];
    __shared__ float Ks[32 * 17];
    const int cs = blockIdx.x, bh = blockIdx.y;
    const int b = bh >> 2, h = bh & 3;
    const int tid = threadIdx.x;
    const int ti = tid & 15, tj = tid >> 4;
    const float* P1 = P + ((size_t)b * C_ + h * DH) * C_;
    const float* Wk = Wqkv + ((size_t)(C_ + h * DH + cs * 16)) * C_;
    float acc[6];
#pragma unroll
    for (int i = 0; i < 6; i++) acc[i] = 0.f;

    for (int k0 = 0; k0 < C_; k0 += 32) {
        __syncthreads();
#pragma unroll
        for (int j = 0; j < 3; j++) {
            int f = tid + 256 * j;
            int row = f >> 3, q = f & 7;
            float4 v = *(const float4*)(P1 + (size_t)row * C_ + k0 + q * 4);
            Ps[(q * 4 + 0) * 97 + row] = v.x;
            Ps[(q * 4 + 1) * 97 + row] = v.y;
            Ps[(q * 4 + 2) * 97 + row] = v.z;
            Ps[(q * 4 + 3) * 97 + row] = v.w;
        }
        {
            int row = tid >> 4, kk = (tid & 15) * 2;
            float2 w = *(const float2*)(Wk + (size_t)row * C_ + k0 + kk);
            Ks[(kk + 0) * 17 + row] = w.x;
            Ks[(kk + 1) * 17 + row] = w.y;
        }
        __syncthreads();
#pragma unroll
        for (int k = 0; k < 32; k++) {
            const float bb = Ks[k * 17 + tj];
#pragma unroll
            for (int i = 0; i < 6; i++)
                acc[i] = fmaf(Ps[k * 97 + ti * 6 + i], bb, acc[i]);
        }
    }
    float* Sb = S + (size_t)bh * DH * DH;
#pragma unroll
    for (int i = 0; i < 6; i++)
        Sb[(size_t)(ti * 6 + i) * DH + cs * 16 + tj] = acc[i];
}

// ---------------------------------------------------------------------------
// S -> attn in place: row r scaled by temp/(nq[r]*nk[c]) then softmax over c.
// ---------------------------------------------------------------------------
__global__ __launch_bounds__(128) void k_soft(float* __restrict__ S,
                                              const float* __restrict__ ssq,
                                              const float* __restrict__ temp) {
    __shared__ float rnk[DH];
    const int bh = blockIdx.x;
    const int b = bh >> 2, h = bh & 3;
    const int r = threadIdx.x;
    if (r < DH)
        rnk[r] = 1.f / fmaxf(sqrtf(ssq[B_ * C_ + b * C_ + h * DH + r]), 1e-12f);
    __syncthreads();
    if (r >= DH) return;
    const float rnq = temp[h] / fmaxf(sqrtf(ssq[b * C_ + h * DH + r]), 1e-12f);
    float* row = S + (size_t)bh * DH * DH + (size_t)r * DH;
    float rv[DH];
    float m = -1e30f;
#pragma unroll
    for (int d = 0; d < DH; d++) {
        rv[d] = row[d] * rnq * rnk[d];
        m = fmaxf(m, rv[d]);
    }
    float s = 0.f;
#pragma unroll
    for (int d = 0; d < DH; d++) { rv[d] = __expf(rv[d] - m); s += rv[d]; }
    const float inv = 1.f / s;
#pragma unroll
    for (int d = 0; d < DH; d++) row[d] = rv[d] * inv;
}

// ---------------------------------------------------------------------------
// T_b[(h,c)][ck] = sum_d attn[b][h][c][d] * Wv[(h,d)][ck]
// ---------------------------------------------------------------------------
__global__ __launch_bounds__(128) void k_T(const float* __restrict__ attn,
                                           const float* __restrict__ Wqkv,
                                           float* __restrict__ T) {
    const int ck = blockIdx.x * 128 + threadIdx.x;
    const int y = blockIdx.y;
    const int b = y / C_, hc = y % C_, h = hc / DH, c = hc % DH;
    const float* ar = attn + ((size_t)(b * NH + h) * DH + c) * DH;
    const float* wv = Wqkv + ((size_t)(2 * C_ + h * DH)) * C_ + ck;
    float s = 0.f;
#pragma unroll 8
    for (int d = 0; d < DH; d++) s = fmaf(ar[d], wv[(size_t)d * C_], s);
    T[((size_t)b * C_ + hc) * C_ + ck] = s;
}

// ---------------------------------------------------------------------------
// Mph[b][m][n] = bf16( sum_k Wout[m][k] * T_b[k][n] )
// ---------------------------------------------------------------------------
__global__ __launch_bounds__(256) void k_Mp64(const float* __restrict__ Wout,
                                              const float* __restrict__ T,
                                              unsigned short* __restrict__ Mph) {
    __shared__ float As[32][65];
    __shared__ float Bs[32][65];
    const int tid = threadIdx.x;
    const int b = blockIdx.z;
    const int m0 = blockIdx.x * 64, n0 = blockIdx.y * 64;
    const float* Tb = T + (size_t)b * C_ * C_;
    const int la_r = tid >> 2, la_k = (tid & 3) * 8;
    const int lb_k = tid >> 3, lb_c = (tid & 7) * 8;
    const int tm = (tid & 15) * 4, tn = (tid >> 4) * 4;
    float acc[4][4];
#pragma unroll
    for (int i = 0; i < 4; i++)
#pragma unroll
        for (int j = 0; j < 4; j++) acc[i][j] = 0.f;

    for (int k0 = 0; k0 < C_; k0 += 32) {
        float4 a0 = *(const float4*)(Wout + (size_t)(m0 + la_r) * C_ + k0 + la_k);
        float4 a1 = *(const float4*)(Wout + (size_t)(m0 + la_r) * C_ + k0 + la_k + 4);
        float4 b0 = *(const float4*)(Tb + (size_t)(k0 + lb_k) * C_ + n0 + lb_c);
        float4 b1 = *(const float4*)(Tb + (size_t)(k0 + lb_k) * C_ + n0 + lb_c + 4);
        __syncthreads();
        As[la_k + 0][la_r] = a0.x; As[la_k + 1][la_r] = a0.y; As[la_k + 2][la_r] = a0.z; As[la_k + 3][la_r] = a0.w;
        As[la_k + 4][la_r] = a1.x; As[la_k + 5][la_r] = a1.y; As[la_k + 6][la_r] = a1.z; As[la_k + 7][la_r] = a1.w;
        *(float4*)&Bs[lb_k][lb_c]     = b0;
        *(float4*)&Bs[lb_k][lb_c + 4] = b1;
        __syncthreads();
#pragma unroll
        for (int k = 0; k < 32; k++) {
            float a[4], bb[4];
            *(float4*)&a[0]  = *(const float4*)&As[k][tm];
            *(float4*)&bb[0] = *(const float4*)&Bs[k][tn];
#pragma unroll
            for (int i = 0; i < 4; i++)
#pragma unroll
                for (int j = 0; j < 4; j++)
                    acc[i][j] = fmaf(a[i], bb[j], acc[i][j]);
        }
    }
    unsigned short* outp = Mph + ((size_t)b * C_ + m0 + tm) * C_ + n0 + tn;
#pragma unroll
    for (int i = 0; i < 4; i++) {
        ushort4v h4;
        h4.x = f2bf(acc[i][0]); h4.y = f2bf(acc[i][1]);
        h4.z = f2bf(acc[i][2]); h4.w = f2bf(acc[i][3]);
        *(ushort4v*)(outp + (size_t)i * C_) = h4;
    }
}

// ---------------------------------------------------------------------------
// out[m][i] = sum_ck Xh[m][ck]*Mph[b][i][ck] + bias[i].  MFMA, K=384.
// ---------------------------------------------------------------------------
__global__ __launch_bounds__(256, 2) void k_out_mfma(const unsigned short* __restrict__ Xh,
                                                     const unsigned short* __restrict__ Mph,
                                                     const float* __restrict__ bias,
                                                     float* __restrict__ out) {
    __shared__ __align__(16) unsigned char sm[32768];
    const int l = blockIdx.x;
    const int xcd = l & 7, k = l >> 3;
    const int mblk = xcd * 64 + k / 3, nblk = k % 3;
    const int m0 = mblk * 128, i0 = nblk * 128;
    const int b = mblk >> 7;
    const int tid = threadIdx.x;
    const int lane = tid & 63, wid = tid >> 6;
    const int wr = wid >> 1, wc = wid & 1;

    const int e = (lane & 7) ^ (lane >> 3);
    const int rsub = lane >> 3;

    const unsigned char* Abase = (const unsigned char*)Xh + (size_t)m0 * (C_ * 2);
    const unsigned char* Bbase = (const unsigned char*)Mph + (size_t)b * (C_ * C_ * 2) + (size_t)i0 * (C_ * 2);

    f32x4 acc[4][4];
#pragma unroll
    for (int i = 0; i < 4; i++)
#pragma unroll
        for (int j = 0; j < 4; j++) acc[i][j] = (f32x4)(0.f);

    for (int ks = 0; ks < 6; ++ks) {
        const size_t colb = (size_t)ks * 128 + (size_t)e * 16;
        __syncthreads();
#pragma unroll
        for (int call = 0; call < 4; ++call) {
            const int row = wid * 32 + call * 8 + rsub;
            load16(Abase + (size_t)row * (C_ * 2) + colb, sm + (wid * 32 + call * 8) * 128);
            load16(Bbase + (size_t)row * (C_ * 2) + colb, sm + 16384 + (wid * 32 + call * 8) * 128);
        }
        __syncthreads();
#pragma unroll
        for (int p = 0; p < 2; ++p) {
            const int s = p * 4 + (lane >> 4);
            short8 av[4], bv[4];
#pragma unroll
            for (int fi = 0; fi < 4; ++fi) {
                const int c = wr * 64 + fi * 16 + (lane & 15);
                av[fi] = *(const short8*)(sm + c * 128 + ((s ^ (c & 7)) << 4));
            }
#pragma unroll
            for (int fj = 0; fj < 4; ++fj) {
                const int c = wc * 64 + fj * 16 + (lane & 15);
                bv[fj] = *(const short8*)(sm + 16384 + c * 128 + ((s ^ (c & 7)) << 4));
            }
#pragma unroll
            for (int fi = 0; fi < 4; ++fi)
#pragma unroll
                for (int fj = 0; fj < 4; ++fj)
                    acc[fi][fj] = __builtin_amdgcn_mfma_f32_16x16x32_bf16(av[fi], bv[fj], acc[fi][fj], 0, 0, 0);
        }
    }
    const int r0 = (lane >> 4) * 4, cc = lane & 15;
#pragma unroll
    for (int fi = 0; fi < 4; ++fi) {
        const int m = m0 + wr * 64 + fi * 16 + r0;
#pragma unroll
        for (int fj = 0; fj < 4; ++fj) {
            const int ii = i0 + wc * 64 + fj * 16 + cc;
            const float bi = bias[ii];
#pragma unroll
            for (int r = 0; r < 4; ++r)
                out[(size_t)(m + r) * C_ + ii] = acc[fi][fj][r] + bi;
        }
    }
}

extern "C" void kernel_launch(void* const* d_in, const int* in_sizes, int n_in,
                              void* d_out, int out_size, void* d_ws, size_t ws_size,
                              hipStream_t stream) {
    const float* x    = (const float*)d_in[0];
    const float* Wqkv = (const float*)d_in[1];
    const float* temp = (const float*)d_in[2];
    const float* Wout = (const float*)d_in[3];
    const float* bout = (const float*)d_in[4];
    float* out = (float*)d_out;

    unsigned char* w8 = (unsigned char*)d_ws;
    unsigned short* Xh  = (unsigned short*)(w8 + XH_B);
    unsigned short* XhT = (unsigned short*)(w8 + XHT_B);
    float* Gpart = (float*)(w8 + GP_B);
    float* G     = (float*)(w8 + G_B);
    float* P     = (float*)(w8 + P_B);
    float* ssq   = (float*)(w8 + SSQ_B);
    float* Satt  = (float*)(w8 + ATT_B);
    float* T     = (float*)(w8 + T_B);
    unsigned short* Mph = (unsigned short*)(w8 + MPH_B);

    k_conv     <<<dim3(256, 6, B_), 256, 0, stream>>>(x, Xh, XhT);
    k_gram_mfma<<<dim3(384), 256, 0, stream>>>(XhT, Gpart);
    k_reduceG  <<<dim3(576), 256, 0, stream>>>(Gpart, G);
    k_P64      <<<dim3(6, 6, 2 * B_), 256, 0, stream>>>(Wqkv, G, P);
    k_diag     <<<dim3(12), 256, 0, stream>>>(P, Wqkv, ssq);
    k_S        <<<dim3(6, B_ * NH), 256, 0, stream>>>(P, Wqkv, Satt);
    k_soft     <<<dim3(B_ * NH), 128, 0, stream>>>(Satt, ssq, temp);
    k_T        <<<dim3(3, B_ * C_), 128, 0, stream>>>(Satt, Wqkv, T);
    k_Mp64     <<<dim3(6, 6, B_), 256, 0, stream>>>(Wout, T, Mph);
    k_out_mfma <<<dim3(1536), 256, 0, stream>>>(Xh, Mph, bout, out);
}

// Round 9
// 390.102 us; speedup vs baseline: 1.0551x; 1.0551x over previous
//
#include <hip/hip_runtime.h>
#include <math.h>

// ============================================================================
// ChannelAttention — Gram restructure, bf16 MFMA big GEMMs.
// R7: split conv into streaming convert (k_convS) + dedicated transpose
//     (k_trans); k_diag folded into k_soft.  Gram/out/P/S/T/Mp unchanged (R6).
// ============================================================================

#define B_    4
#define NTOK  16384
#define C_    384
#define NH    4
#define DH    96

typedef __attribute__((ext_vector_type(8))) short short8;
typedef __attribute__((ext_vector_type(4))) float f32x4;
typedef __attribute__((ext_vector_type(4))) unsigned short ushort4v;
typedef __attribute__((ext_vector_type(8))) unsigned short ushort8v;
typedef __attribute__((ext_vector_type(4))) unsigned int uint4v;

// ---- ws byte offsets (ws = 384 MiB) ----
#define XH_B   0ull
#define XHT_B  50331648ull            // + B*N*C*2
#define GP_B   100663296ull           // 16 grp partials (chunk x batch), fp32
#define G_B    138412032ull
#define P_B    140771328ull
#define ATT_B  145502208ull           // S, then attn in-place (16*96*96 f32)
#define T_B    146092032ull           // T (4*384*384 f32)
#define MPH_B  150810624ull

__device__ inline unsigned short f2bf(float f) {
    unsigned u = __float_as_uint(f);
    u += 0x7FFFu + ((u >> 16) & 1u);          // RNE
    return (unsigned short)(u >> 16);
}

__device__ inline void load16(const void* g, void* l) {
    __builtin_amdgcn_global_load_lds(
        (const __attribute__((address_space(1))) unsigned int*)g,
        (__attribute__((address_space(3))) unsigned int*)l, 16, 0, 0);
}

// ---------------------------------------------------------------------------
// Streaming X fp32 -> Xh bf16.  No LDS, no sync.  grid-stride, 2048 blocks.
// ---------------------------------------------------------------------------
__global__ __launch_bounds__(256) void k_convS(const float* __restrict__ X,
                                               unsigned short* __restrict__ Xh) {
    const size_t n4 = (size_t)B_ * NTOK * C_ / 4;
    const size_t stride = (size_t)gridDim.x * 256;
    for (size_t i = (size_t)blockIdx.x * 256 + threadIdx.x; i < n4; i += stride) {
        const float4 v = *(const float4*)(X + i * 4);
        ushort4v h;
        h.x = f2bf(v.x); h.y = f2bf(v.y); h.z = f2bf(v.z); h.w = f2bf(v.w);
        *(ushort4v*)(Xh + i * 4) = h;
    }
}

// ---------------------------------------------------------------------------
// Xh [b][t][c] -> XhT [b][c][t].  128t x 128c tiles, u32 token-pair LDS.
// grid (128 t-tiles, 3 c-tiles, 4 b), 256 threads.
// ---------------------------------------------------------------------------
__global__ __launch_bounds__(256) void k_trans(const unsigned short* __restrict__ Xh,
                                               unsigned short* __restrict__ XhT) {
    __shared__ unsigned int Tp[64 * 129];     // [token-pair][128 ch + pad]
    const int tid = threadIdx.x;
    const int t0 = blockIdx.x * 128, c0 = blockIdx.y * 128, b = blockIdx.z;
    const int cg = tid & 15;                  // 8-ch group
#pragma unroll
    for (int p = 0; p < 4; ++p) {
        const int tp = (tid >> 4) + 16 * p;   // token pair 0..63
        const int t = t0 + tp * 2;
        const ushort8v r0 = *(const ushort8v*)(Xh + ((size_t)(b * NTOK + t))     * C_ + c0 + cg * 8);
        const ushort8v r1 = *(const ushort8v*)(Xh + ((size_t)(b * NTOK + t + 1)) * C_ + c0 + cg * 8);
#pragma unroll
        for (int j = 0; j < 8; ++j)
            Tp[tp * 129 + cg * 8 + j] = (unsigned)r0[j] | ((unsigned)r1[j] << 16);
    }
    __syncthreads();
    const int qtr = tid & 3;                  // token quarter (32 tokens = 16 u32)
#pragma unroll
    for (int p = 0; p < 2; ++p) {
        const int c = (tid >> 2) + 64 * p;    // channel row 0..127
        unsigned int w[16];
#pragma unroll
        for (int m = 0; m < 16; ++m)
            w[m] = Tp[(qtr * 16 + m) * 129 + c];
        unsigned int* dst = (unsigned int*)(XhT + ((size_t)(b * C_ + c0 + c)) * NTOK + t0 + qtr * 32);
#pragma unroll
        for (int i = 0; i < 4; ++i) {
            uint4v s4; s4.x = w[i*4+0]; s4.y = w[i*4+1]; s4.z = w[i*4+2]; s4.w = w[i*4+3];
            *((uint4v*)dst + i) = s4;
        }
    }
}

// ---------------------------------------------------------------------------
// Gpart[grp]: 6 lower-triangle 128x128 tiles of XhT-stripe @ XhT-stripe^T
// over a 1024-token chunk (MFMA 16x16x32).  Off-diag tiles mirror-stored.
// 384 blocks (8 grps x 6 tiles per XCD), 4 waves.  [unchanged, R6-proven]
// ---------------------------------------------------------------------------
__global__ __launch_bounds__(256, 2) void k_gram_mfma(const unsigned short* __restrict__ XhT,
                                                      float* __restrict__ Gpart) {
    __shared__ __align__(16) unsigned char sm[32768];
    const int l = blockIdx.x;
    const int xcd = l & 7, slot = l >> 3;
    const int grp = xcd * 8 + slot / 6, tile = slot % 6;
    const int chunk = grp >> 2, b = grp & 3;
    const int ti = (tile == 0) ? 0 : (tile < 3 ? 1 : 2);
    const int tj = tile - (ti * (ti + 1)) / 2;
    const int tid = threadIdx.x;
    const int lane = tid & 63, wid = tid >> 6;
    const int wr = wid >> 1, wc = wid & 1;

    const int e = (lane & 7) ^ (lane >> 3);
    const int rsub = lane >> 3;

    const size_t rowb = (size_t)NTOK * 2;
    const unsigned char* Abase = (const unsigned char*)XhT + (size_t)(b * C_ + ti * 128) * rowb;
    const unsigned char* Bbase = (const unsigned char*)XhT + (size_t)(b * C_ + tj * 128) * rowb;

    f32x4 acc[4][4];
#pragma unroll
    for (int i = 0; i < 4; i++)
#pragma unroll
        for (int j = 0; j < 4; j++) acc[i][j] = (f32x4)(0.f);

    for (int ks = 0; ks < 16; ++ks) {
        const size_t colb = (size_t)(chunk * 1024 + ks * 64) * 2 + (size_t)e * 16;
        __syncthreads();
#pragma unroll
        for (int call = 0; call < 4; ++call) {
            const int row = wid * 32 + call * 8 + rsub;
            load16(Abase + (size_t)row * rowb + colb, sm + (wid * 32 + call * 8) * 128);
            load16(Bbase + (size_t)row * rowb + colb, sm + 16384 + (wid * 32 + call * 8) * 128);
        }
        __syncthreads();
#pragma unroll
        for (int p = 0; p < 2; ++p) {
            const int s = p * 4 + (lane >> 4);
            short8 av[4], bv[4];
#pragma unroll
            for (int fi = 0; fi < 4; ++fi) {
                const int c = wr * 64 + fi * 16 + (lane & 15);
                av[fi] = *(const short8*)(sm + c * 128 + ((s ^ (c & 7)) << 4));
            }
#pragma unroll
            for (int fj = 0; fj < 4; ++fj) {
                const int c = wc * 64 + fj * 16 + (lane & 15);
                bv[fj] = *(const short8*)(sm + 16384 + c * 128 + ((s ^ (c & 7)) << 4));
            }
#pragma unroll
            for (int fi = 0; fi < 4; ++fi)
#pragma unroll
                for (int fj = 0; fj < 4; ++fj)
                    acc[fi][fj] = __builtin_amdgcn_mfma_f32_16x16x32_bf16(av[fi], bv[fj], acc[fi][fj], 0, 0, 0);
        }
    }
    float* gp = Gpart + (size_t)grp * (C_ * C_);
    const int r0 = (lane >> 4) * 4, cc = lane & 15;
#pragma unroll
    for (int fi = 0; fi < 4; ++fi) {
        const int ci = ti * 128 + wr * 64 + fi * 16 + r0;
#pragma unroll
        for (int fj = 0; fj < 4; ++fj) {
            const int cj = tj * 128 + wc * 64 + fj * 16 + cc;
#pragma unroll
            for (int r = 0; r < 4; ++r)
                gp[(size_t)(ci + r) * C_ + cj] = acc[fi][fj][r];
        }
    }
    if (ti != tj) {
#pragma unroll
        for (int fi = 0; fi < 4; ++fi) {
            const int cib = ti * 128 + wr * 64 + fi * 16 + r0;
#pragma unroll
            for (int fj = 0; fj < 4; ++fj) {
                const int cjb = tj * 128 + wc * 64 + fj * 16 + cc;
                *(f32x4*)(gp + (size_t)cjb * C_ + cib) = acc[fi][fj];
            }
        }
    }
}

__global__ __launch_bounds__(256) void k_reduceG(const float* __restrict__ Gpart,
                                                 float* __restrict__ G) {
    const size_t eo = ((size_t)blockIdx.x * 256 + threadIdx.x) * 4;
    float4 s = *(const float4*)(Gpart + eo);
#pragma unroll
    for (int c = 1; c < 16; ++c) {
        const float4 v = *(const float4*)(Gpart + (size_t)c * (B_ * C_ * C_) + eo);
        s.x += v.x; s.y += v.y; s.z += v.z; s.w += v.w;
    }
    *(float4*)(G + eo) = s;
}

// ---------------------------------------------------------------------------
// P[sel][b][m][n] = sum_k W_sel[m][k] * G_b[n][k]   (G symmetric)
// ---------------------------------------------------------------------------
__global__ __launch_bounds__(256) void k_P64(const float* __restrict__ Wqkv,
                                             const float* __restrict__ G,
                                             float* __restrict__ P) {
    __shared__ float As[32][65];
    __shared__ float Bs[32][65];
    const int tid = threadIdx.x;
    const int sel = blockIdx.z & 1, b = blockIdx.z >> 1;
    const int m0 = blockIdx.x * 64, n0 = blockIdx.y * 64;
    const float* A  = Wqkv + (size_t)sel * C_ * C_;
    const float* Bm = G + (size_t)b * C_ * C_;
    const int lr = tid >> 2, lk = (tid & 3) * 8;
    const int tm = (tid & 15) * 4, tn = (tid >> 4) * 4;
    float acc[4][4];
#pragma unroll
    for (int i = 0; i < 4; i++)
#pragma unroll
        for (int j = 0; j < 4; j++) acc[i][j] = 0.f;

    for (int k0 = 0; k0 < C_; k0 += 32) {
        float4 a0 = *(const float4*)(A  + (size_t)(m0 + lr) * C_ + k0 + lk);
        float4 a1 = *(const float4*)(A  + (size_t)(m0 + lr) * C_ + k0 + lk + 4);
        float4 b0 = *(const float4*)(Bm + (size_t)(n0 + lr) * C_ + k0 + lk);
        float4 b1 = *(const float4*)(Bm + (size_t)(n0 + lr) * C_ + k0 + lk + 4);
        __syncthreads();
        As[lk + 0][lr] = a0.x; As[lk + 1][lr] = a0.y; As[lk + 2][lr] = a0.z; As[lk + 3][lr] = a0.w;
        As[lk + 4][lr] = a1.x; As[lk + 5][lr] = a1.y; As[lk + 6][lr] = a1.z; As[lk + 7][lr] = a1.w;
        Bs[lk + 0][lr] = b0.x; Bs[lk + 1][lr] = b0.y; Bs[lk + 2][lr] = b0.z; Bs[lk + 3][lr] = b0.w;
        Bs[lk + 4][lr] = b1.x; Bs[lk + 5][lr] = b1.y; Bs[lk + 6][lr] = b1.z; Bs[lk + 7][lr] = b1.w;
        __syncthreads();
#pragma unroll
        for (int k = 0; k < 32; k++) {
            float a[4], bb[4];
            *(float4*)&a[0]  = *(const float4*)&As[k][tm];
            *(float4*)&bb[0] = *(const float4*)&Bs[k][tn];
#pragma unroll
            for (int i = 0; i < 4; i++)
#pragma unroll
                for (int j = 0; j < 4; j++)
                    acc[i][j] = fmaf(a[i], bb[j], acc[i][j]);
        }
    }
    float* outp = P + ((size_t)(sel * B_ + b) * C_ + m0 + tm) * C_ + n0 + tn;
#pragma unroll
    for (int i = 0; i < 4; i++) {
        float4 c0 = make_float4(acc[i][0], acc[i][1], acc[i][2], acc[i][3]);
        *(float4*)(outp + (size_t)i * C_) = c0;
    }
}

// ---------------------------------------------------------------------------
// S[bh][r][c] = sum_k P1[b][h*96+r][k] * Wk[h*96+c][k]
// ---------------------------------------------------------------------------
__global__ __launch_bounds__(256) void k_S(const float* __restrict__ P,
                                           const float* __restrict__ Wqkv,
                                           float* __restrict__ S) {
    __shared__ float Ps[32 * 97];
    __shared__ float Ks[32 * 17];
    const int cs = blockIdx.x, bh = blockIdx.y;
    const int b = bh >> 2, h = bh & 3;
    const int tid = threadIdx.x;
    const int ti = tid & 15, tj = tid >> 4;
    const float* P1 = P + ((size_t)b * C_ + h * DH) * C_;
    const float* Wk = Wqkv + ((size_t)(C_ + h * DH + cs * 16)) * C_;
    float acc[6];
#pragma unroll
    for (int i = 0; i < 6; i++) acc[i] = 0.f;

    for (int k0 = 0; k0 < C_; k0 += 32) {
        __syncthreads();
#pragma unroll
        for (int j = 0; j < 3; j++) {
            int f = tid + 256 * j;
            int row = f >> 3, q = f & 7;
            float4 v = *(const float4*)(P1 + (size_t)row * C_ + k0 + q * 4);
            Ps[(q * 4 + 0) * 97 + row] = v.x;
            Ps[(q * 4 + 1) * 97 + row] = v.y;
            Ps[(q * 4 + 2) * 97 + row] = v.z;
            Ps[(q * 4 + 3) * 97 + row] = v.w;
        }
        {
            int row = tid >> 4, kk = (tid & 15) * 2;
            float2 w = *(const float2*)(Wk + (size_t)row * C_ + k0 + kk);
            Ks[(kk + 0) * 17 + row] = w.x;
            Ks[(kk + 1) * 17 + row] = w.y;
        }
        __syncthreads();
#pragma unroll
        for (int k = 0; k < 32; k++) {
            const float bb = Ks[k * 17 + tj];
#pragma unroll
            for (int i = 0; i < 6; i++)
                acc[i] = fmaf(Ps[k * 97 + ti * 6 + i], bb, acc[i]);
        }
    }
    float* Sb = S + (size_t)bh * DH * DH;
#pragma unroll
    for (int i = 0; i < 6; i++)
        Sb[(size_t)(ti * 6 + i) * DH + cs * 16 + tj] = acc[i];
}

// ---------------------------------------------------------------------------
// S -> attn in place.  Norms computed inline (k_diag deleted):
//   nk[r] = ||k row|| from <P2[r], Wk[r]>, nq from <P1[r], Wq[r]>.
// ---------------------------------------------------------------------------
__global__ __launch_bounds__(128) void k_soft(float* __restrict__ S,
                                              const float* __restrict__ P,
                                              const float* __restrict__ Wqkv,
                                              const float* __restrict__ temp) {
    __shared__ float rnk[DH];
    const int bh = blockIdx.x;
    const int b = bh >> 2, h = bh & 3;
    const int r = threadIdx.x;
    if (r < DH) {
        const float* p2 = P + ((size_t)(B_ + b) * C_ + h * DH + r) * C_;   // sel=1
        const float* wk = Wqkv + ((size_t)(C_ + h * DH + r)) * C_;
        float s = 0.f;
#pragma unroll 4
        for (int k = 0; k < C_; k += 4) {
            const float4 pv = *(const float4*)(p2 + k);
            const float4 wv = *(const float4*)(wk + k);
            s += pv.x * wv.x + pv.y * wv.y + pv.z * wv.z + pv.w * wv.w;
        }
        rnk[r] = 1.f / fmaxf(sqrtf(s), 1e-12f);
    }
    __syncthreads();
    if (r >= DH) return;
    float sq = 0.f;
    {
        const float* p1 = P + ((size_t)b * C_ + h * DH + r) * C_;          // sel=0
        const float* wq = Wqkv + ((size_t)(h * DH + r)) * C_;
#pragma unroll 4
        for (int k = 0; k < C_; k += 4) {
            const float4 pv = *(const float4*)(p1 + k);
            const float4 wv = *(const float4*)(wq + k);
            sq += pv.x * wv.x + pv.y * wv.y + pv.z * wv.z + pv.w * wv.w;
        }
    }
    const float rnq = temp[h] / fmaxf(sqrtf(sq), 1e-12f);
    float* row = S + (size_t)bh * DH * DH + (size_t)r * DH;
    float rv[DH];
    float m = -1e30f;
#pragma unroll
    for (int d = 0; d < DH; d++) {
        rv[d] = row[d] * rnq * rnk[d];
        m = fmaxf(m, rv[d]);
    }
    float s = 0.f;
#pragma unroll
    for (int d = 0; d < DH; d++) { rv[d] = __expf(rv[d] - m); s += rv[d]; }
    const float inv = 1.f / s;
#pragma unroll
    for (int d = 0; d < DH; d++) row[d] = rv[d] * inv;
}

// ---------------------------------------------------------------------------
// T_b[(h,c)][ck] = sum_d attn[b][h][c][d] * Wv[(h,d)][ck]
// ---------------------------------------------------------------------------
__global__ __launch_bounds__(128) void k_T(const float* __restrict__ attn,
                                           const float* __restrict__ Wqkv,
                                           float* __restrict__ T) {
    const int ck = blockIdx.x * 128 + threadIdx.x;
    const int y = blockIdx.y;
    const int b = y / C_, hc = y % C_, h = hc / DH, c = hc % DH;
    const float* ar = attn + ((size_t)(b * NH + h) * DH + c) * DH;
    const float* wv = Wqkv + ((size_t)(2 * C_ + h * DH)) * C_ + ck;
    float s = 0.f;
#pragma unroll 8
    for (int d = 0; d < DH; d++) s = fmaf(ar[d], wv[(size_t)d * C_], s);
    T[((size_t)b * C_ + hc) * C_ + ck] = s;
}

// ---------------------------------------------------------------------------
// Mph[b][m][n] = bf16( sum_k Wout[m][k] * T_b[k][n] )
// ---------------------------------------------------------------------------
__global__ __launch_bounds__(256) void k_Mp64(const float* __restrict__ Wout,
                                              const float* __restrict__ T,
                                              unsigned short* __restrict__ Mph) {
    __shared__ float As[32][65];
    __shared__ float Bs[32][65];
    const int tid = threadIdx.x;
    const int b = blockIdx.z;
    const int m0 = blockIdx.x * 64, n0 = blockIdx.y * 64;
    const float* Tb = T + (size_t)b * C_ * C_;
    const int la_r = tid >> 2, la_k = (tid & 3) * 8;
    const int lb_k = tid >> 3, lb_c = (tid & 7) * 8;
    const int tm = (tid & 15) * 4, tn = (tid >> 4) * 4;
    float acc[4][4];
#pragma unroll
    for (int i = 0; i < 4; i++)
#pragma unroll
        for (int j = 0; j < 4; j++) acc[i][j] = 0.f;

    for (int k0 = 0; k0 < C_; k0 += 32) {
        float4 a0 = *(const float4*)(Wout + (size_t)(m0 + la_r) * C_ + k0 + la_k);
        float4 a1 = *(const float4*)(Wout + (size_t)(m0 + la_r) * C_ + k0 + la_k + 4);
        float4 b0 = *(const float4*)(Tb + (size_t)(k0 + lb_k) * C_ + n0 + lb_c);
        float4 b1 = *(const float4*)(Tb + (size_t)(k0 + lb_k) * C_ + n0 + lb_c + 4);
        __syncthreads();
        As[la_k + 0][la_r] = a0.x; As[la_k + 1][la_r] = a0.y; As[la_k + 2][la_r] = a0.z; As[la_k + 3][la_r] = a0.w;
        As[la_k + 4][la_r] = a1.x; As[la_k + 5][la_r] = a1.y; As[la_k + 6][la_r] = a1.z; As[la_k + 7][la_r] = a1.w;
        *(float4*)&Bs[lb_k][lb_c]     = b0;
        *(float4*)&Bs[lb_k][lb_c + 4] = b1;
        __syncthreads();
#pragma unroll
        for (int k = 0; k < 32; k++) {
            float a[4], bb[4];
            *(float4*)&a[0]  = *(const float4*)&As[k][tm];
            *(float4*)&bb[0] = *(const float4*)&Bs[k][tn];
#pragma unroll
            for (int i = 0; i < 4; i++)
#pragma unroll
                for (int j = 0; j < 4; j++)
                    acc[i][j] = fmaf(a[i], bb[j], acc[i][j]);
        }
    }
    unsigned short* outp = Mph + ((size_t)b * C_ + m0 + tm) * C_ + n0 + tn;
#pragma unroll
    for (int i = 0; i < 4; i++) {
        ushort4v h4;
        h4.x = f2bf(acc[i][0]); h4.y = f2bf(acc[i][1]);
        h4.z = f2bf(acc[i][2]); h4.w = f2bf(acc[i][3]);
        *(ushort4v*)(outp + (size_t)i * C_) = h4;
    }
}

// ---------------------------------------------------------------------------
// out[m][i] = sum_ck Xh[m][ck]*Mph[b][i][ck] + bias[i].  MFMA, K=384.
// ---------------------------------------------------------------------------
__global__ __launch_bounds__(256, 2) void k_out_mfma(const unsigned short* __restrict__ Xh,
                                                     const unsigned short* __restrict__ Mph,
                                                     const float* __restrict__ bias,
                                                     float* __restrict__ out) {
    __shared__ __align__(16) unsigned char sm[32768];
    const int l = blockIdx.x;
    const int xcd = l & 7, k = l >> 3;
    const int mblk = xcd * 64 + k / 3, nblk = k % 3;
    const int m0 = mblk * 128, i0 = nblk * 128;
    const int b = mblk >> 7;
    const int tid = threadIdx.x;
    const int lane = tid & 63, wid = tid >> 6;
    const int wr = wid >> 1, wc = wid & 1;

    const int e = (lane & 7) ^ (lane >> 3);
    const int rsub = lane >> 3;

    const unsigned char* Abase = (const unsigned char*)Xh + (size_t)m0 * (C_ * 2);
    const unsigned char* Bbase = (const unsigned char*)Mph + (size_t)b * (C_ * C_ * 2) + (size_t)i0 * (C_ * 2);

    f32x4 acc[4][4];
#pragma unroll
    for (int i = 0; i < 4; i++)
#pragma unroll
        for (int j = 0; j < 4; j++) acc[i][j] = (f32x4)(0.f);

    for (int ks = 0; ks < 6; ++ks) {
        const size_t colb = (size_t)ks * 128 + (size_t)e * 16;
        __syncthreads();
#pragma unroll
        for (int call = 0; call < 4; ++call) {
            const int row = wid * 32 + call * 8 + rsub;
            load16(Abase + (size_t)row * (C_ * 2) + colb, sm + (wid * 32 + call * 8) * 128);
            load16(Bbase + (size_t)row * (C_ * 2) + colb, sm + 16384 + (wid * 32 + call * 8) * 128);
        }
        __syncthreads();
#pragma unroll
        for (int p = 0; p < 2; ++p) {
            const int s = p * 4 + (lane >> 4);
            short8 av[4], bv[4];
#pragma unroll
            for (int fi = 0; fi < 4; ++fi) {
                const int c = wr * 64 + fi * 16 + (lane & 15);
                av[fi] = *(const short8*)(sm + c * 128 + ((s ^ (c & 7)) << 4));
            }
#pragma unroll
            for (int fj = 0; fj < 4; ++fj) {
                const int c = wc * 64 + fj * 16 + (lane & 15);
                bv[fj] = *(const short8*)(sm + 16384 + c * 128 + ((s ^ (c & 7)) << 4));
            }
#pragma unroll
            for (int fi = 0; fi < 4; ++fi)
#pragma unroll
                for (int fj = 0; fj < 4; ++fj)
                    acc[fi][fj] = __builtin_amdgcn_mfma_f32_16x16x32_bf16(av[fi], bv[fj], acc[fi][fj], 0, 0, 0);
        }
    }
    const int r0 = (lane >> 4) * 4, cc = lane & 15;
#pragma unroll
    for (int fi = 0; fi < 4; ++fi) {
        const int m = m0 + wr * 64 + fi * 16 + r0;
#pragma unroll
        for (int fj = 0; fj < 4; ++fj) {
            const int ii = i0 + wc * 64 + fj * 16 + cc;
            const float bi = bias[ii];
#pragma unroll
            for (int r = 0; r < 4; ++r)
                out[(size_t)(m + r) * C_ + ii] = acc[fi][fj][r] + bi;
        }
    }
}

extern "C" void kernel_launch(void* const* d_in, const int* in_sizes, int n_in,
                              void* d_out, int out_size, void* d_ws, size_t ws_size,
                              hipStream_t stream) {
    const float* x    = (const float*)d_in[0];
    const float* Wqkv = (const float*)d_in[1];
    const float* temp = (const float*)d_in[2];
    const float* Wout = (const float*)d_in[3];
    const float* bout = (const float*)d_in[4];
    float* out = (float*)d_out;

    unsigned char* w8 = (unsigned char*)d_ws;
    unsigned short* Xh  = (unsigned short*)(w8 + XH_B);
    unsigned short* XhT = (unsigned short*)(w8 + XHT_B);
    float* Gpart = (float*)(w8 + GP_B);
    float* G     = (float*)(w8 + G_B);
    float* P     = (float*)(w8 + P_B);
    float* Satt  = (float*)(w8 + ATT_B);
    float* T     = (float*)(w8 + T_B);
    unsigned short* Mph = (unsigned short*)(w8 + MPH_B);

    k_convS    <<<dim3(2048), 256, 0, stream>>>(x, Xh);
    k_trans    <<<dim3(128, 3, B_), 256, 0, stream>>>(Xh, XhT);
    k_gram_mfma<<<dim3(384), 256, 0, stream>>>(XhT, Gpart);
    k_reduceG  <<<dim3(576), 256, 0, stream>>>(Gpart, G);
    k_P64      <<<dim3(6, 6, 2 * B_), 256, 0, stream>>>(Wqkv, G, P);
    k_S        <<<dim3(6, B_ * NH), 256, 0, stream>>>(P, Wqkv, Satt);
    k_soft     <<<dim3(B_ * NH), 128, 0, stream>>>(Satt, P, Wqkv, temp);
    k_T        <<<dim3(3, B_ * C_), 128, 0, stream>>>(Satt, Wqkv, T);
    k_Mp64     <<<dim3(6, 6, B_), 256, 0, stream>>>(Wout, T, Mph);
    k_out_mfma <<<dim3(1536), 256, 0, stream>>>(Xh, Mph, bout, out);
}